// Round 9
// baseline (312.642 us; speedup 1.0000x reference)
//
#include <hip/hip_runtime.h>

#define N_NODES 40000
#define M_PAD   40064   // 313 * 128
#define N_EDGES 320000
#define N_GRAPHS 64
#define IN_DIM 128
#define HID4 256
#define OUT_DIM 128
#define LN_EPS 1e-5f

typedef short  s16x8  __attribute__((ext_vector_type(8)));
typedef __bf16 bf16x8 __attribute__((ext_vector_type(8)));
typedef float  f32x4  __attribute__((ext_vector_type(4)));

__device__ __forceinline__ unsigned short f2b(float f) {
    unsigned int u = __builtin_bit_cast(unsigned int, f);
    u += 0x7fffu + ((u >> 16) & 1u);   // round-to-nearest-even
    return (unsigned short)(u >> 16);
}
__device__ __forceinline__ float b2f(unsigned short h) {
    unsigned int u = (unsigned int)h << 16;
    return __builtin_bit_cast(float, u);
}
__device__ __forceinline__ float lo2f(unsigned int u) { return b2f((unsigned short)u); }
__device__ __forceinline__ float hi2f(unsigned int u) { return b2f((unsigned short)(u >> 16)); }
__device__ __forceinline__ unsigned int packb(float x, float y) {
    return (unsigned int)f2b(x) | ((unsigned int)f2b(y) << 16);
}

// direct global->LDS 16B DMA; lds base wave-uniform, HW scatters lane*16
__device__ __forceinline__ void gll16(const unsigned short* g, short* lds_base) {
    __builtin_amdgcn_global_load_lds(
        (const __attribute__((address_space(1))) unsigned int*)g,
        (__attribute__((address_space(3))) unsigned int*)lds_base, 16, 0, 0);
}

#define MFMA_BF16(a, b, c) __builtin_amdgcn_mfma_f32_16x16x32_bf16( \
    __builtin_bit_cast(bf16x8, a), __builtin_bit_cast(bf16x8, b), c, 0, 0, 0)

// ---------------- fused prep: x->bf16, weights->bf16 transposed, edge ew + histograms ----
// cnt_in atomicAdd's return (edge's rank within its dst bucket) is stored to rank[],
// making csr_fill atomic-free (R8 win: -11 us).

#define XN (N_NODES * IN_DIM)          // 5,120,000
#define XT (XN / 8)                    // 640,000 threads, 8 elems each
#define WN 229376                      // 32768*3 + 131072
#define PREP_TOT (XT + WN + N_EDGES)

__global__ void prep_all(const float* __restrict__ x, const float* __restrict__ W1,
                         const float* __restrict__ fc1, const float* __restrict__ W2,
                         const float* __restrict__ W3, const float* __restrict__ w,
                         const int* __restrict__ src, const int* __restrict__ dst,
                         unsigned short* __restrict__ xb, unsigned short* __restrict__ W1t,
                         unsigned short* __restrict__ fc1t, unsigned short* __restrict__ W2t,
                         unsigned short* __restrict__ W3t, float* __restrict__ ew,
                         int* __restrict__ cnt_out, int* __restrict__ cnt_in,
                         int* __restrict__ rank) {
    int idx = blockIdx.x * 256 + threadIdx.x;
    if (idx < XT) {
        const float4* xv = (const float4*)x;
        float4 u = xv[idx * 2], v = xv[idx * 2 + 1];
        uint4 o;
        o.x = packb(u.x, u.y); o.y = packb(u.z, u.w);
        o.z = packb(v.x, v.y); o.w = packb(v.z, v.w);
        ((uint4*)xb)[idx] = o;
        return;
    }
    int j = idx - XT;
    if (j < 32768) { int k = j >> 8, n = j & 255; W1t[n * 128 + k] = f2b(W1[j]); return; }
    j -= 32768;
    if (j < 32768) { int k = j >> 8, n = j & 255; fc1t[n * 128 + k] = f2b(fc1[j]); return; }
    j -= 32768;
    if (j < 131072) { int k = j >> 8, n = j & 255; W2t[n * 512 + k] = f2b(W2[j]); return; }
    j -= 131072;
    if (j < 32768) { int k = j >> 7, n = j & 127; W3t[n * 256 + k] = f2b(W3[j]); return; }
    j -= 32768;
    if (j < N_EDGES) {
        float4 v = ((const float4*)w)[j];
        ew[j] = fmaxf(fmaxf(v.x, v.y), fmaxf(v.z, v.w));
        atomicAdd(&cnt_out[src[j]], 1);
        rank[j] = atomicAdd(&cnt_in[dst[j]], 1);   // rank within dst bucket
    }
}

// stage 1: 40 blocks x 256 threads, block b sums cnt[b*1000 .. b*1000+999]
__global__ void scan_part(const int* __restrict__ cnt, int* __restrict__ partial) {
    int b = blockIdx.x;
    int s = 0;
    for (int i = threadIdx.x; i < 1000; i += 256) s += cnt[b * 1000 + i];
#pragma unroll
    for (int m = 1; m < 64; m <<= 1) s += __shfl_xor(s, m);
    __shared__ int wsm[4];
    if ((threadIdx.x & 63) == 0) wsm[threadIdx.x >> 6] = s;
    __syncthreads();
    if (threadIdx.x == 0) partial[b] = wsm[0] + wsm[1] + wsm[2] + wsm[3];
}

// stage 2: 40 blocks x 1024 threads; exclusive scan -> off ; also inv-sqrt degrees
__global__ void scan_final(const int* __restrict__ cnt_in, const int* __restrict__ cnt_out,
                           const int* __restrict__ partial, int* __restrict__ off,
                           float* __restrict__ out_inv, float* __restrict__ in_inv) {
    int b = blockIdx.x, tid = threadIdx.x;
    int lane = tid & 63, wv = tid >> 6;
    int pre = 0;
    for (int j = 0; j < b; ++j) pre += partial[j];
    int i = b * 1000 + tid;
    int v = (tid < 1000) ? cnt_in[i] : 0;
    int x = v;
#pragma unroll
    for (int ofs = 1; ofs < 64; ofs <<= 1) {
        int t = __shfl_up(x, ofs);
        if (lane >= ofs) x += t;
    }
    __shared__ int wsum[16];
    if (lane == 63) wsum[wv] = x;
    __syncthreads();
    if (wv == 0 && lane < 16) {
        int s = wsum[lane];
#pragma unroll
        for (int ofs = 1; ofs < 16; ofs <<= 1) {
            int t = __shfl_up(s, ofs);
            if (lane >= ofs) s += t;
        }
        wsum[lane] = s;
    }
    __syncthreads();
    int incl = pre + (wv > 0 ? wsum[wv - 1] : 0) + x;
    if (tid < 1000) {
        off[i] = incl - v;   // exclusive
        in_inv[i] = rsqrtf(fmaxf((float)v, 1.0f));
        out_inv[i] = rsqrtf(fmaxf((float)cnt_out[i], 1.0f));
    }
    if (b == 39 && tid == 999) off[N_NODES] = incl;
}

// atomic-free scatter: slot = off[dst] + rank (rank precomputed in prep_all)
__global__ void csr_fill(const int* __restrict__ src, const int* __restrict__ dst,
                         const float* __restrict__ ew, const float* __restrict__ out_inv,
                         const int* __restrict__ off, const int* __restrict__ rank,
                         int4* __restrict__ es) {
    int e = blockIdx.x * 256 + threadIdx.x;
    if (e >= N_EDGES) return;
    int d = dst[e];
    int slot = off[d] + rank[e];
    int s = src[e];
    float wv = ew[e];
    es[slot] = make_int4(s, __float_as_int(wv * out_inv[s]), __float_as_int(wv), 0);
}

// ---- hetero launch: fc1 GEMM+LN (blocks [0,313), MFMA-bound) + gather1 (blocks
// [313,5313), latency-bound, MFMA idle). Pipe-complementary: fc1's matrix work hides
// under gather1's memory latency. fc1 blocks placed FIRST so they're resident from t=0.
// Gather inner loop byte-identical to R8's proven D=128 half-split 2-deep branch.

__global__ __launch_bounds__(512) void g1_fc1(
    const unsigned short* __restrict__ xb, const int* __restrict__ off,
    const int4* __restrict__ es, const float* __restrict__ in_inv,
    unsigned short* __restrict__ agg1b,
    const unsigned short* __restrict__ fc1t, unsigned short* __restrict__ f1b,
    const float* __restrict__ gamma, const float* __restrict__ beta) {
    __shared__ short As[4096];   // [128][32]
    __shared__ short Bs[8192];   // [256][32]
    __shared__ float lns[128][4];
    __shared__ float lnq[128][4];
    int tid = threadIdx.x;
    int lane = tid & 63, wave = tid >> 6;      // 0..7

    if (blockIdx.x >= 313) {
        // ---- gather1: one node per wave ----
        int n = (blockIdx.x - 313) * 8 + wave;
        if (n >= N_NODES) return;
        int b = off[n], e = off[n + 1];
        const uint2* hu = (const uint2*)xb;
        int half = lane >> 5, cl = lane & 31;
        float a0 = 0.f, a1 = 0.f, a2 = 0.f, a3 = 0.f;
        int i = b;
        for (; i + 3 < e; i += 4) {
            int4 ea = es[i + half];
            int4 eb = es[i + 2 + half];
            uint2 pa = hu[(size_t)ea.x * 32 + cl];
            uint2 pb = hu[(size_t)eb.x * 32 + cl];
            float wa = __int_as_float(ea.y);
            float wb = __int_as_float(eb.y);
            a0 += wa * lo2f(pa.x) + wb * lo2f(pb.x);
            a1 += wa * hi2f(pa.x) + wb * hi2f(pb.x);
            a2 += wa * lo2f(pa.y) + wb * lo2f(pb.y);
            a3 += wa * hi2f(pa.y) + wb * hi2f(pb.y);
        }
        for (; i < e; i += 2) {
            int idx = i + half;
            int4 ee = es[idx < e ? idx : i];
            float w = (idx < e) ? __int_as_float(ee.y) : 0.0f;
            uint2 p = hu[(size_t)ee.x * 32 + cl];
            a0 += w * lo2f(p.x); a1 += w * hi2f(p.x);
            a2 += w * lo2f(p.y); a3 += w * hi2f(p.y);
        }
        a0 += __shfl_xor(a0, 32); a1 += __shfl_xor(a1, 32);
        a2 += __shfl_xor(a2, 32); a3 += __shfl_xor(a3, 32);
        float sc = in_inv[n];
        a0 *= sc; a1 *= sc; a2 *= sc; a3 *= sc;
        if (half == 0) {
            uint2 o; o.x = packb(a0, a1); o.y = packb(a2, a3);
            ((uint2*)agg1b)[(size_t)n * 32 + cl] = o;
        }
        return;
    }

    // ---- fc1: 128x256 tile, K=128, LayerNorm(affine)+relu epilogue ----
    int m0 = blockIdx.x * 128;
    int wm = (wave >> 2) * 64, wn = (wave & 3) * 64;
    int quad = lane >> 4, r16 = lane & 15;
    f32x4 acc[4][4] = {};
    int lrow = lane >> 2;
    int kc = (lane & 3) * 8;
    short* ldsA = As + wave * 512;
    short* ldsB = Bs + wave * 512;

    for (int k0 = 0; k0 < 128; k0 += 32) {
        int kk = k0 + kc;
        int rr = wave * 16 + lrow;  // 0..127
        gll16(xb + (size_t)(m0 + rr) * 128 + kk, ldsA);
        gll16(fc1t + (size_t)rr * 128 + kk, ldsB);
        gll16(fc1t + (size_t)(128 + rr) * 128 + kk, ldsB + 4096);
        __syncthreads();
        s16x8 af[4], bfr[4];
#pragma unroll
        for (int i = 0; i < 4; ++i)
            af[i] = *(const s16x8*)(As + (wm + i * 16 + r16) * 32 + quad * 8);
#pragma unroll
        for (int j = 0; j < 4; ++j)
            bfr[j] = *(const s16x8*)(Bs + (wn + j * 16 + r16) * 32 + quad * 8);
#pragma unroll
        for (int i = 0; i < 4; ++i)
#pragma unroll
            for (int j = 0; j < 4; ++j)
                acc[i][j] = MFMA_BF16(af[i], bfr[j], acc[i][j]);
        __syncthreads();
    }

#pragma unroll
    for (int i = 0; i < 4; ++i)
#pragma unroll
        for (int r = 0; r < 4; ++r) {
            float s = 0.0f, q = 0.0f;
#pragma unroll
            for (int j = 0; j < 4; ++j) { float v = acc[i][j][r]; s += v; q += v * v; }
#pragma unroll
            for (int m = 1; m < 16; m <<= 1) { s += __shfl_xor(s, m); q += __shfl_xor(q, m); }
            if (r16 == 0) {
                int row = wm + i * 16 + quad * 4 + r;
                lns[row][wave & 3] = s;
                lnq[row][wave & 3] = q;
            }
        }
    __syncthreads();
#pragma unroll
    for (int i = 0; i < 4; ++i) {
#pragma unroll
        for (int r = 0; r < 4; ++r) {
            int row = wm + i * 16 + quad * 4 + r;
            float s = lns[row][0] + lns[row][1] + lns[row][2] + lns[row][3];
            float q = lnq[row][0] + lnq[row][1] + lnq[row][2] + lnq[row][3];
            float mu = s * (1.0f / HID4);
            float var = q * (1.0f / HID4) - mu * mu;
            float rs = rsqrtf(var + LN_EPS);
            int m = m0 + row;
#pragma unroll
            for (int j = 0; j < 4; ++j) {
                int col = wn + j * 16 + r16;
                float v = (acc[i][j][r] - mu) * rs * gamma[col] + beta[col];
                f1b[(size_t)m * 256 + col] = f2b(fmaxf(v, 0.0f));
            }
        }
    }
}

// ---------------- gather aggregation (block = 1 wave per dst node) — R8-measured ----------
// D=256: lane covers cols 4*lane..4*lane+3 (uint2), full 512B row/instr, 4 edges deep.

template <int D, int RELU, int WSEL>
__global__ void gather_nodes(const unsigned short* __restrict__ h, const int* __restrict__ off,
                             const int4* __restrict__ eg, const float* __restrict__ scale,
                             unsigned short* __restrict__ outb) {
    int n = blockIdx.x;
    int lane = threadIdx.x;   // 64 threads
    int b = off[n], e = off[n + 1];
    const uint2* hu = (const uint2*)h;
    float a0 = 0.f, a1 = 0.f, a2 = 0.f, a3 = 0.f;
    if constexpr (D == 256) {
        int i = b;
        for (; i + 3 < e; i += 4) {
            int4 e0 = eg[i], e1 = eg[i + 1], e2 = eg[i + 2], e3 = eg[i + 3];
            uint2 p0 = hu[(size_t)e0.x * 64 + lane];
            uint2 p1 = hu[(size_t)e1.x * 64 + lane];
            uint2 p2 = hu[(size_t)e2.x * 64 + lane];
            uint2 p3 = hu[(size_t)e3.x * 64 + lane];
            float w0 = __int_as_float(WSEL ? e0.z : e0.y);
            float w1 = __int_as_float(WSEL ? e1.z : e1.y);
            float w2 = __int_as_float(WSEL ? e2.z : e2.y);
            float w3 = __int_as_float(WSEL ? e3.z : e3.y);
            a0 += w0 * lo2f(p0.x) + w1 * lo2f(p1.x) + w2 * lo2f(p2.x) + w3 * lo2f(p3.x);
            a1 += w0 * hi2f(p0.x) + w1 * hi2f(p1.x) + w2 * hi2f(p2.x) + w3 * hi2f(p3.x);
            a2 += w0 * lo2f(p0.y) + w1 * lo2f(p1.y) + w2 * lo2f(p2.y) + w3 * lo2f(p3.y);
            a3 += w0 * hi2f(p0.y) + w1 * hi2f(p1.y) + w2 * hi2f(p2.y) + w3 * hi2f(p3.y);
        }
        for (; i < e; ++i) {
            int4 ee = eg[i];
            uint2 p = hu[(size_t)ee.x * 64 + lane];
            float w0 = __int_as_float(WSEL ? ee.z : ee.y);
            a0 += w0 * lo2f(p.x); a1 += w0 * hi2f(p.x);
            a2 += w0 * lo2f(p.y); a3 += w0 * hi2f(p.y);
        }
        float sc = scale[n];
        a0 *= sc; a1 *= sc; a2 *= sc; a3 *= sc;
        if (RELU) {
            a0 = fmaxf(a0, 0.f); a1 = fmaxf(a1, 0.f);
            a2 = fmaxf(a2, 0.f); a3 = fmaxf(a3, 0.f);
        }
        uint2 o; o.x = packb(a0, a1); o.y = packb(a2, a3);
        ((uint2*)outb)[(size_t)n * 64 + lane] = o;
    } else {  // D == 128
        int half = lane >> 5, cl = lane & 31;
        int i = b;
        for (; i + 3 < e; i += 4) {
            int4 ea = eg[i + half];
            int4 eb = eg[i + 2 + half];
            uint2 pa = hu[(size_t)ea.x * 32 + cl];
            uint2 pb = hu[(size_t)eb.x * 32 + cl];
            float wa = __int_as_float(WSEL ? ea.z : ea.y);
            float wb = __int_as_float(WSEL ? eb.z : eb.y);
            a0 += wa * lo2f(pa.x) + wb * lo2f(pb.x);
            a1 += wa * hi2f(pa.x) + wb * hi2f(pb.x);
            a2 += wa * lo2f(pa.y) + wb * lo2f(pb.y);
            a3 += wa * hi2f(pa.y) + wb * hi2f(pb.y);
        }
        for (; i < e; i += 2) {
            int idx = i + half;
            int4 ee = eg[idx < e ? idx : i];            // clamp: keep addr valid
            float w = (idx < e) ? __int_as_float(WSEL ? ee.z : ee.y) : 0.0f;
            uint2 p = hu[(size_t)ee.x * 32 + cl];
            a0 += w * lo2f(p.x); a1 += w * hi2f(p.x);
            a2 += w * lo2f(p.y); a3 += w * hi2f(p.y);
        }
        a0 += __shfl_xor(a0, 32); a1 += __shfl_xor(a1, 32);
        a2 += __shfl_xor(a2, 32); a3 += __shfl_xor(a3, 32);
        float sc = scale[n];
        a0 *= sc; a1 *= sc; a2 *= sc; a3 *= sc;
        if (RELU) {
            a0 = fmaxf(a0, 0.f); a1 = fmaxf(a1, 0.f);
            a2 = fmaxf(a2, 0.f); a3 = fmaxf(a3, 0.f);
        }
        if (half == 0) {
            uint2 o; o.x = packb(a0, a1); o.y = packb(a2, a3);
            ((uint2*)outb)[(size_t)n * 32 + cl] = o;
        }
    }
}

// ---------------- gather conv3 + fused readout (8 nodes/block, run-length atomics) ------
// NO device-scope fences here (R5 lesson: they destroy L2/L3 residency of Q3b/es).

#define G3_NPB 8

__global__ void gather3_ro(const unsigned short* __restrict__ h, const int* __restrict__ off,
                           const int4* __restrict__ eg, const float* __restrict__ scale,
                           const int* __restrict__ gid, float* __restrict__ ro) {
    int lane = threadIdx.x;   // 64
    int half = lane >> 5, cl = lane & 31;   // cols 4cl..4cl+3 via uint2, half-split edges
    int n0 = blockIdx.x * G3_NPB;
    int n1 = n0 + G3_NPB;
    if (n1 > N_NODES) n1 = N_NODES;
    const uint2* hu = (const uint2*)h;   // row stride 32 (128 bf16)
    float r0 = 0.f, r1 = 0.f, r2 = 0.f, r3 = 0.f;
    int cur = gid[n0];
    for (int n = n0; n < n1; ++n) {
        int g = gid[n];
        if (g != cur) {
            atomicAdd(&ro[cur * OUT_DIM + 4 * cl + 2 * half], half ? r2 : r0);
            atomicAdd(&ro[cur * OUT_DIM + 4 * cl + 2 * half + 1], half ? r3 : r1);
            r0 = r1 = r2 = r3 = 0.f;
            cur = g;
        }
        int b = off[n], e = off[n + 1];
        float a0 = 0.f, a1 = 0.f, a2 = 0.f, a3 = 0.f;
        int i = b;
        for (; i + 3 < e; i += 4) {
            int4 ea = eg[i + half];
            int4 eb = eg[i + 2 + half];
            uint2 pa = hu[(size_t)ea.x * 32 + cl];
            uint2 pb = hu[(size_t)eb.x * 32 + cl];
            float wa = __int_as_float(ea.z), wb = __int_as_float(eb.z);
            a0 += wa * lo2f(pa.x) + wb * lo2f(pb.x);
            a1 += wa * hi2f(pa.x) + wb * hi2f(pb.x);
            a2 += wa * lo2f(pa.y) + wb * lo2f(pb.y);
            a3 += wa * hi2f(pa.y) + wb * hi2f(pb.y);
        }
        for (; i < e; i += 2) {
            int idx = i + half;
            int4 ee = eg[idx < e ? idx : i];
            float w = (idx < e) ? __int_as_float(ee.z) : 0.0f;
            uint2 p = hu[(size_t)ee.x * 32 + cl];
            a0 += w * lo2f(p.x); a1 += w * hi2f(p.x);
            a2 += w * lo2f(p.y); a3 += w * hi2f(p.y);
        }
        a0 += __shfl_xor(a0, 32); a1 += __shfl_xor(a1, 32);
        a2 += __shfl_xor(a2, 32); a3 += __shfl_xor(a3, 32);
        float sc = scale[n];
        r0 += fmaxf(a0 * sc, 0.0f); r1 += fmaxf(a1 * sc, 0.0f);
        r2 += fmaxf(a2 * sc, 0.0f); r3 += fmaxf(a3 * sc, 0.0f);
    }
    atomicAdd(&ro[cur * OUT_DIM + 4 * cl + 2 * half], half ? r2 : r0);
    atomicAdd(&ro[cur * OUT_DIM + 4 * cl + 2 * half + 1], half ? r3 : r1);
}

// ---------------- MFMA bf16 GEMM core: 128x128 tile, BK=64, swizzled global_load_lds ------

__device__ __forceinline__ void gemm_core(short* As, short* Bs,
    const unsigned short* __restrict__ A, const unsigned short* __restrict__ A2,
    const unsigned short* __restrict__ Bt, unsigned short* __restrict__ C,
    const float* __restrict__ rowScaleC, int K1, int K2, int N,
    int relu, int scaleC, int m0, int n0) {
    int tid = threadIdx.x;
    int lane = tid & 63, wave = tid >> 6;
    int wm = (wave >> 1) * 64, wn = (wave & 1) * 64;
    int quad = lane >> 4, r16 = lane & 15;
    const int K = K1 + K2;
    f32x4 acc[4][4] = {};
    int srow = lane >> 3;                     // 0..7 (row within 8-row DMA group)
    int sk   = ((lane & 7) ^ srow) * 8;       // swizzled source k-chunk (elems)
    int xorc = r16 & 7;
    short* ldsA = As + wave * 2048;           // wave stages rows [wave*32, wave*32+32)
    short* ldsB = Bs + wave * 2048;

    for (int k0 = 0; k0 < K; k0 += 64) {
        int kk = k0 + sk;
#pragma unroll
        for (int h = 0; h < 4; ++h) {
            int r = wave * 32 + h * 8 + srow;
            const unsigned short* Ap = (k0 < K1)
                ? A  + (size_t)(m0 + r) * K1 + kk
                : A2 + (size_t)(m0 + r) * K2 + (kk - K1);
            gll16(Ap, ldsA + h * 512);
            gll16(Bt + (size_t)(n0 + r) * K + kk, ldsB + h * 512);
        }
        __syncthreads();
#pragma unroll
        for (int c = 0; c < 2; ++c) {
            s16x8 af[4], bfr[4];
            int pc = (((c * 4 + quad) ^ xorc) << 3);
#pragma unroll
            for (int i = 0; i < 4; ++i)
                af[i] = *(const s16x8*)(As + (wm + i * 16 + r16) * 64 + pc);
#pragma unroll
            for (int j = 0; j < 4; ++j)
                bfr[j] = *(const s16x8*)(Bs + (wn + j * 16 + r16) * 64 + pc);
#pragma unroll
            for (int i = 0; i < 4; ++i)
#pragma unroll
                for (int j = 0; j < 4; ++j)
                    acc[i][j] = MFMA_BF16(af[i], bfr[j], acc[i][j]);
        }
        __syncthreads();
    }

#pragma unroll
    for (int i = 0; i < 4; ++i) {
        int mbase = m0 + wm + i * 16 + quad * 4;
#pragma unroll
        for (int r = 0; r < 4; ++r) {
            int m = mbase + r;
            float sc = scaleC ? rowScaleC[m] : 1.0f;
#pragma unroll
            for (int j = 0; j < 4; ++j) {
                float v = acc[i][j][r] * sc;
                if (relu) v = fmaxf(v, 0.0f);
                C[(size_t)m * N + n0 + wn + j * 16 + r16] = f2b(v);
            }
        }
    }
}

template <int RELU, int SCALE_C>
__global__ __launch_bounds__(256) void gemm_mfma(
    const unsigned short* __restrict__ A, const unsigned short* __restrict__ A2,
    const unsigned short* __restrict__ Bt, unsigned short* __restrict__ C,
    const float* __restrict__ rowScaleC, int K1, int K2, int N) {
    __shared__ short As[8192];
    __shared__ short Bs[8192];
    gemm_core(As, Bs, A, A2, Bt, C, rowScaleC, K1, K2, N, RELU, SCALE_C,
              blockIdx.x * 128, blockIdx.y * 128);
}

// -------- conv1 GEMM: 128x256 tile, 512 threads, K=128, relu ----

__global__ __launch_bounds__(512) void gemm_conv1(
    const unsigned short* __restrict__ A, const unsigned short* __restrict__ Bt,
    unsigned short* __restrict__ C) {
    __shared__ short As[4096];   // [128][32]
    __shared__ short Bs[8192];   // [256][32]
    int tid = threadIdx.x;
    int lane = tid & 63, wave = tid >> 6;      // 0..7
    int wm = (wave >> 2) * 64, wn = (wave & 3) * 64;
    int quad = lane >> 4, r16 = lane & 15;
    int m0 = blockIdx.x * 128;
    f32x4 acc[4][4] = {};
    int lrow = lane >> 2;
    int kc = (lane & 3) * 8;
    short* ldsA = As + wave * 512;
    short* ldsB = Bs + wave * 512;

    for (int k0 = 0; k0 < 128; k0 += 32) {
        int kk = k0 + kc;
        int rr = wave * 16 + lrow;  // 0..127
        gll16(A + (size_t)(m0 + rr) * 128 + kk, ldsA);
        gll16(Bt + (size_t)rr * 128 + kk, ldsB);
        gll16(Bt + (size_t)(128 + rr) * 128 + kk, ldsB + 4096);
        __syncthreads();
        s16x8 af[4], bfr[4];
#pragma unroll
        for (int i = 0; i < 4; ++i)
            af[i] = *(const s16x8*)(As + (wm + i * 16 + r16) * 32 + quad * 8);
#pragma unroll
        for (int j = 0; j < 4; ++j)
            bfr[j] = *(const s16x8*)(Bs + (wn + j * 16 + r16) * 32 + quad * 8);
#pragma unroll
        for (int i = 0; i < 4; ++i)
#pragma unroll
            for (int j = 0; j < 4; ++j)
                acc[i][j] = MFMA_BF16(af[i], bfr[j], acc[i][j]);
        __syncthreads();
    }

#pragma unroll
    for (int i = 0; i < 4; ++i) {
        int mbase = m0 + wm + i * 16 + quad * 4;
#pragma unroll
        for (int r = 0; r < 4; ++r) {
            int m = mbase + r;
#pragma unroll
            for (int j = 0; j < 4; ++j)
                C[(size_t)m * 256 + wn + j * 16 + r16] = f2b(fmaxf(acc[i][j][r], 0.0f));
        }
    }
}

// ---------------- normalize ----------------

__global__ void normalize_out(const float* __restrict__ ro, float* __restrict__ out) {
    int g = blockIdx.x;
    int d = threadIdx.x;  // 128 threads = 2 waves
    float v = ro[g * OUT_DIM + d];
    float ss = v * v;
#pragma unroll
    for (int m = 1; m < 64; m <<= 1) ss += __shfl_xor(ss, m);
    __shared__ float s2[2];
    if ((d & 63) == 0) s2[d >> 6] = ss;
    __syncthreads();
    float tot = s2[0] + s2[1];
    float norm = fmaxf(sqrtf(tot), 1e-12f);
    out[g * OUT_DIM + d] = v / norm;
}

// ---------------- launch ----------------

extern "C" void kernel_launch(void* const* d_in, const int* in_sizes, int n_in,
                              void* d_out, int out_size, void* d_ws, size_t ws_size,
                              hipStream_t stream) {
    const float* x    = (const float*)d_in[0];
    const float* w    = (const float*)d_in[1];
    const float* W1   = (const float*)d_in[2];
    const float* fc1W = (const float*)d_in[3];
    const float* gam  = (const float*)d_in[4];
    const float* bet  = (const float*)d_in[5];
    const float* W2   = (const float*)d_in[6];
    const float* W3   = (const float*)d_in[7];
    const int* src = (const int*)d_in[8];
    const int* dst = (const int*)d_in[9];
    const int* gid = (const int*)d_in[10];
    float* out = (float*)d_out;

    float* ws = (float*)d_ws;
    float* out_inv = ws + 0;                                 // 40000
    float* in_inv  = ws + 40000;                             // 40000
    float* ew      = ws + 80000;                             // 320000
    int*   cnt_out = (int*)(ws + 400000);                    // 40000 (memset group start)
    int*   cnt_in  = (int*)(ws + 440000);                    // 40000 (memset group)
    float* ro      = ws + 480000;                            // 8192 (memset group end)
    unsigned short* W1t  = (unsigned short*)(ws + 488192);   // [256][128]
    unsigned short* fc1t = (unsigned short*)(ws + 504576);   // [256][128]
    unsigned short* W2t  = (unsigned short*)(ws + 520960);   // [256][512]
    unsigned short* W3t  = (unsigned short*)(ws + 586496);   // [128][256]
    int*   partial = (int*)(ws + 602880);                    // 40
    int*   off     = (int*)(ws + 602920);                    // 40001 ints
    int4*  es      = (int4*)(ws + 642924);                   // 320000 int4 (16B-aligned)
    unsigned short* xb    = (unsigned short*)(ws + 1923000); // [M_PAD][128] ; later Q3b
    unsigned short* Q3b   = xb;
    unsigned short* agg1b = (unsigned short*)(ws + 4487100); // [M_PAD][128..256] ; later x2b
    unsigned short* x2b   = agg1b;
    unsigned short* x1b   = (unsigned short*)(ws + 9615300); // [M_PAD][256]
    unsigned short* f1b   = (unsigned short*)(ws + 14743500);// [M_PAD][256]
    unsigned short* P2b   = (unsigned short*)(ws + 19871700);// [M_PAD][256]
    int*   rank    = (int*)(ws + 25000000);                  // 320000 ints

    // one memset covers cnt_out | cnt_in | ro (contiguous)
    hipMemsetAsync(cnt_out, 0, (2 * 40000 + N_GRAPHS * OUT_DIM) * sizeof(float), stream);

    // fused conversions + edge weights + degree histograms (+ per-edge dst-bucket rank)
    prep_all<<<(PREP_TOT + 255) / 256, 256, 0, stream>>>(x, W1, fc1W, W2, W3, w, src, dst,
                                                         xb, W1t, fc1t, W2t, W3t, ew,
                                                         cnt_out, cnt_in, rank);
    scan_part<<<40, 256, 0, stream>>>(cnt_in, partial);
    scan_final<<<40, 1024, 0, stream>>>(cnt_in, cnt_out, partial, off, out_inv, in_inv);
    // atomic-free CSR scatter
    csr_fill<<<(N_EDGES + 255) / 256, 256, 0, stream>>>(src, dst, ew, out_inv, off, rank, es);

    // hetero: fc1 GEMM+LN (313 blocks, MFMA) hidden under gather1 (5000 blocks, latency)
    g1_fc1<<<313 + 5000, 512, 0, stream>>>(xb, off, es, in_inv, agg1b,
                                           fc1t, f1b, gam, bet);
    // conv1 GEMM (agg1b @ W1t -> x1b, relu)
    gemm_conv1<<<313, 512, 0, stream>>>(agg1b, W1t, x1b);

    // conv2
    {
        dim3 grid(M_PAD / 128, HID4 / 128);
        gemm_mfma<0, 1><<<grid, 256, 0, stream>>>(x1b, f1b, W2t, P2b, out_inv,
                                                  HID4, HID4, HID4);
    }
    gather_nodes<HID4, 1, 1><<<N_NODES, 64, 0, stream>>>(P2b, off, es, in_inv, x2b);

    // conv3
    {
        dim3 grid(M_PAD / 128, OUT_DIM / 128);
        gemm_mfma<0, 1><<<grid, 256, 0, stream>>>(x2b, nullptr, W3t, Q3b, out_inv,
                                                  HID4, 0, OUT_DIM);
    }
    // conv3 gather fused with readout (x3 never materialized)
    gather3_ro<<<(N_NODES + G3_NPB - 1) / G3_NPB, 64, 0, stream>>>(Q3b, off, es, in_inv,
                                                                   gid, ro);
    normalize_out<<<N_GRAPHS, 128, 0, stream>>>(ro, out);
}

// Round 10
// 273.184 us; speedup vs baseline: 1.1444x; 1.1444x over previous
//
#include <hip/hip_runtime.h>

#define N_NODES 40000
#define M_PAD   40064   // 313 * 128
#define N_EDGES 320000
#define N_GRAPHS 64
#define IN_DIM 128
#define HID4 256
#define OUT_DIM 128
#define LN_EPS 1e-5f

typedef short  s16x8  __attribute__((ext_vector_type(8)));
typedef __bf16 bf16x8 __attribute__((ext_vector_type(8)));
typedef float  f32x4  __attribute__((ext_vector_type(4)));

__device__ __forceinline__ unsigned short f2b(float f) {
    unsigned int u = __builtin_bit_cast(unsigned int, f);
    u += 0x7fffu + ((u >> 16) & 1u);   // round-to-nearest-even
    return (unsigned short)(u >> 16);
}
__device__ __forceinline__ float b2f(unsigned short h) {
    unsigned int u = (unsigned int)h << 16;
    return __builtin_bit_cast(float, u);
}
__device__ __forceinline__ float lo2f(unsigned int u) { return b2f((unsigned short)u); }
__device__ __forceinline__ float hi2f(unsigned int u) { return b2f((unsigned short)(u >> 16)); }
__device__ __forceinline__ unsigned int packb(float x, float y) {
    return (unsigned int)f2b(x) | ((unsigned int)f2b(y) << 16);
}

// direct global->LDS 16B DMA; lds base wave-uniform, HW scatters lane*16
__device__ __forceinline__ void gll16(const unsigned short* g, short* lds_base) {
    __builtin_amdgcn_global_load_lds(
        (const __attribute__((address_space(1))) unsigned int*)g,
        (__attribute__((address_space(3))) unsigned int*)lds_base, 16, 0, 0);
}

#define MFMA_BF16(a, b, c) __builtin_amdgcn_mfma_f32_16x16x32_bf16( \
    __builtin_bit_cast(bf16x8, a), __builtin_bit_cast(bf16x8, b), c, 0, 0, 0)

// ---------------- fused prep: x->bf16, weights->bf16 transposed, edge ew + histograms ----
// cnt_in atomicAdd's return (edge's rank within its dst bucket) is stored to rank[],
// making csr_fill atomic-free (R8 win: -11 us).

#define XN (N_NODES * IN_DIM)          // 5,120,000
#define XT (XN / 8)                    // 640,000 threads, 8 elems each
#define WN 229376                      // 32768*3 + 131072
#define PREP_TOT (XT + WN + N_EDGES)

__global__ void prep_all(const float* __restrict__ x, const float* __restrict__ W1,
                         const float* __restrict__ fc1, const float* __restrict__ W2,
                         const float* __restrict__ W3, const float* __restrict__ w,
                         const int* __restrict__ src, const int* __restrict__ dst,
                         unsigned short* __restrict__ xb, unsigned short* __restrict__ W1t,
                         unsigned short* __restrict__ fc1t, unsigned short* __restrict__ W2t,
                         unsigned short* __restrict__ W3t, float* __restrict__ ew,
                         int* __restrict__ cnt_out, int* __restrict__ cnt_in,
                         int* __restrict__ rank) {
    int idx = blockIdx.x * 256 + threadIdx.x;
    if (idx < XT) {
        const float4* xv = (const float4*)x;
        float4 u = xv[idx * 2], v = xv[idx * 2 + 1];
        uint4 o;
        o.x = packb(u.x, u.y); o.y = packb(u.z, u.w);
        o.z = packb(v.x, v.y); o.w = packb(v.z, v.w);
        ((uint4*)xb)[idx] = o;
        return;
    }
    int j = idx - XT;
    if (j < 32768) { int k = j >> 8, n = j & 255; W1t[n * 128 + k] = f2b(W1[j]); return; }
    j -= 32768;
    if (j < 32768) { int k = j >> 8, n = j & 255; fc1t[n * 128 + k] = f2b(fc1[j]); return; }
    j -= 32768;
    if (j < 131072) { int k = j >> 8, n = j & 255; W2t[n * 512 + k] = f2b(W2[j]); return; }
    j -= 131072;
    if (j < 32768) { int k = j >> 7, n = j & 127; W3t[n * 256 + k] = f2b(W3[j]); return; }
    j -= 32768;
    if (j < N_EDGES) {
        float4 v = ((const float4*)w)[j];
        ew[j] = fmaxf(fmaxf(v.x, v.y), fmaxf(v.z, v.w));
        atomicAdd(&cnt_out[src[j]], 1);
        rank[j] = atomicAdd(&cnt_in[dst[j]], 1);   // rank within dst bucket
    }
}

// stage 1: 40 blocks x 256 threads, block b sums cnt[b*1000 .. b*1000+999]
__global__ void scan_part(const int* __restrict__ cnt, int* __restrict__ partial) {
    int b = blockIdx.x;
    int s = 0;
    for (int i = threadIdx.x; i < 1000; i += 256) s += cnt[b * 1000 + i];
#pragma unroll
    for (int m = 1; m < 64; m <<= 1) s += __shfl_xor(s, m);
    __shared__ int wsm[4];
    if ((threadIdx.x & 63) == 0) wsm[threadIdx.x >> 6] = s;
    __syncthreads();
    if (threadIdx.x == 0) partial[b] = wsm[0] + wsm[1] + wsm[2] + wsm[3];
}

// stage 2: 40 blocks x 1024 threads; exclusive scan -> off ; also inv-sqrt degrees
__global__ void scan_final(const int* __restrict__ cnt_in, const int* __restrict__ cnt_out,
                           const int* __restrict__ partial, int* __restrict__ off,
                           float* __restrict__ out_inv, float* __restrict__ in_inv) {
    int b = blockIdx.x, tid = threadIdx.x;
    int lane = tid & 63, wv = tid >> 6;
    int pre = 0;
    for (int j = 0; j < b; ++j) pre += partial[j];
    int i = b * 1000 + tid;
    int v = (tid < 1000) ? cnt_in[i] : 0;
    int x = v;
#pragma unroll
    for (int ofs = 1; ofs < 64; ofs <<= 1) {
        int t = __shfl_up(x, ofs);
        if (lane >= ofs) x += t;
    }
    __shared__ int wsum[16];
    if (lane == 63) wsum[wv] = x;
    __syncthreads();
    if (wv == 0 && lane < 16) {
        int s = wsum[lane];
#pragma unroll
        for (int ofs = 1; ofs < 16; ofs <<= 1) {
            int t = __shfl_up(s, ofs);
            if (lane >= ofs) s += t;
        }
        wsum[lane] = s;
    }
    __syncthreads();
    int incl = pre + (wv > 0 ? wsum[wv - 1] : 0) + x;
    if (tid < 1000) {
        off[i] = incl - v;   // exclusive
        in_inv[i] = rsqrtf(fmaxf((float)v, 1.0f));
        out_inv[i] = rsqrtf(fmaxf((float)cnt_out[i], 1.0f));
    }
    if (b == 39 && tid == 999) off[N_NODES] = incl;
}

// atomic-free scatter: slot = off[dst] + rank (rank precomputed in prep_all)
__global__ void csr_fill(const int* __restrict__ src, const int* __restrict__ dst,
                         const float* __restrict__ ew, const float* __restrict__ out_inv,
                         const int* __restrict__ off, const int* __restrict__ rank,
                         int4* __restrict__ es) {
    int e = blockIdx.x * 256 + threadIdx.x;
    if (e >= N_EDGES) return;
    int d = dst[e];
    int slot = off[d] + rank[e];
    int s = src[e];
    float wv = ew[e];
    es[slot] = make_int4(s, __float_as_int(wv * out_inv[s]), __float_as_int(wv), 0);
}

// ---------------- gather aggregation (block = 1 wave per dst node) — R8-measured ----------
// D=256: lane covers cols 4*lane..4*lane+3 (uint2), full 512B row/instr, 4 edges deep.
// D=128: lanes 0-31 edge i, lanes 32-63 edge i+1 (uint2), 2-deep, shfl-combine.

template <int D, int RELU, int WSEL>
__global__ void gather_nodes(const unsigned short* __restrict__ h, const int* __restrict__ off,
                             const int4* __restrict__ eg, const float* __restrict__ scale,
                             unsigned short* __restrict__ outb) {
    int n = blockIdx.x;
    int lane = threadIdx.x;   // 64 threads
    int b = off[n], e = off[n + 1];
    const uint2* hu = (const uint2*)h;
    float a0 = 0.f, a1 = 0.f, a2 = 0.f, a3 = 0.f;
    if constexpr (D == 256) {
        int i = b;
        for (; i + 3 < e; i += 4) {
            int4 e0 = eg[i], e1 = eg[i + 1], e2 = eg[i + 2], e3 = eg[i + 3];
            uint2 p0 = hu[(size_t)e0.x * 64 + lane];
            uint2 p1 = hu[(size_t)e1.x * 64 + lane];
            uint2 p2 = hu[(size_t)e2.x * 64 + lane];
            uint2 p3 = hu[(size_t)e3.x * 64 + lane];
            float w0 = __int_as_float(WSEL ? e0.z : e0.y);
            float w1 = __int_as_float(WSEL ? e1.z : e1.y);
            float w2 = __int_as_float(WSEL ? e2.z : e2.y);
            float w3 = __int_as_float(WSEL ? e3.z : e3.y);
            a0 += w0 * lo2f(p0.x) + w1 * lo2f(p1.x) + w2 * lo2f(p2.x) + w3 * lo2f(p3.x);
            a1 += w0 * hi2f(p0.x) + w1 * hi2f(p1.x) + w2 * hi2f(p2.x) + w3 * hi2f(p3.x);
            a2 += w0 * lo2f(p0.y) + w1 * lo2f(p1.y) + w2 * lo2f(p2.y) + w3 * lo2f(p3.y);
            a3 += w0 * hi2f(p0.y) + w1 * hi2f(p1.y) + w2 * hi2f(p2.y) + w3 * hi2f(p3.y);
        }
        for (; i < e; ++i) {
            int4 ee = eg[i];
            uint2 p = hu[(size_t)ee.x * 64 + lane];
            float w0 = __int_as_float(WSEL ? ee.z : ee.y);
            a0 += w0 * lo2f(p.x); a1 += w0 * hi2f(p.x);
            a2 += w0 * lo2f(p.y); a3 += w0 * hi2f(p.y);
        }
        float sc = scale[n];
        a0 *= sc; a1 *= sc; a2 *= sc; a3 *= sc;
        if (RELU) {
            a0 = fmaxf(a0, 0.f); a1 = fmaxf(a1, 0.f);
            a2 = fmaxf(a2, 0.f); a3 = fmaxf(a3, 0.f);
        }
        uint2 o; o.x = packb(a0, a1); o.y = packb(a2, a3);
        ((uint2*)outb)[(size_t)n * 64 + lane] = o;
    } else {  // D == 128
        int half = lane >> 5, cl = lane & 31;
        int i = b;
        for (; i + 3 < e; i += 4) {
            int4 ea = eg[i + half];
            int4 eb = eg[i + 2 + half];
            uint2 pa = hu[(size_t)ea.x * 32 + cl];
            uint2 pb = hu[(size_t)eb.x * 32 + cl];
            float wa = __int_as_float(WSEL ? ea.z : ea.y);
            float wb = __int_as_float(WSEL ? eb.z : eb.y);
            a0 += wa * lo2f(pa.x) + wb * lo2f(pb.x);
            a1 += wa * hi2f(pa.x) + wb * hi2f(pb.x);
            a2 += wa * lo2f(pa.y) + wb * lo2f(pb.y);
            a3 += wa * hi2f(pa.y) + wb * hi2f(pb.y);
        }
        for (; i < e; i += 2) {
            int idx = i + half;
            int4 ee = eg[idx < e ? idx : i];            // clamp: keep addr valid
            float w = (idx < e) ? __int_as_float(WSEL ? ee.z : ee.y) : 0.0f;
            uint2 p = hu[(size_t)ee.x * 32 + cl];
            a0 += w * lo2f(p.x); a1 += w * hi2f(p.x);
            a2 += w * lo2f(p.y); a3 += w * hi2f(p.y);
        }
        a0 += __shfl_xor(a0, 32); a1 += __shfl_xor(a1, 32);
        a2 += __shfl_xor(a2, 32); a3 += __shfl_xor(a3, 32);
        float sc = scale[n];
        a0 *= sc; a1 *= sc; a2 *= sc; a3 *= sc;
        if (RELU) {
            a0 = fmaxf(a0, 0.f); a1 = fmaxf(a1, 0.f);
            a2 = fmaxf(a2, 0.f); a3 = fmaxf(a3, 0.f);
        }
        if (half == 0) {
            uint2 o; o.x = packb(a0, a1); o.y = packb(a2, a3);
            ((uint2*)outb)[(size_t)n * 32 + cl] = o;
        }
    }
}

// ---------------- gather conv3 + fused readout (8 nodes/block, run-length atomics) ------
// NO device-scope fences here (R5 lesson: they destroy L2/L3 residency of Q3b/es).

#define G3_NPB 8

__global__ void gather3_ro(const unsigned short* __restrict__ h, const int* __restrict__ off,
                           const int4* __restrict__ eg, const float* __restrict__ scale,
                           const int* __restrict__ gid, float* __restrict__ ro) {
    int lane = threadIdx.x;   // 64
    int half = lane >> 5, cl = lane & 31;   // cols 4cl..4cl+3 via uint2, half-split edges
    int n0 = blockIdx.x * G3_NPB;
    int n1 = n0 + G3_NPB;
    if (n1 > N_NODES) n1 = N_NODES;
    const uint2* hu = (const uint2*)h;   // row stride 32 (128 bf16)
    float r0 = 0.f, r1 = 0.f, r2 = 0.f, r3 = 0.f;
    int cur = gid[n0];
    for (int n = n0; n < n1; ++n) {
        int g = gid[n];
        if (g != cur) {
            atomicAdd(&ro[cur * OUT_DIM + 4 * cl + 2 * half], half ? r2 : r0);
            atomicAdd(&ro[cur * OUT_DIM + 4 * cl + 2 * half + 1], half ? r3 : r1);
            r0 = r1 = r2 = r3 = 0.f;
            cur = g;
        }
        int b = off[n], e = off[n + 1];
        float a0 = 0.f, a1 = 0.f, a2 = 0.f, a3 = 0.f;
        int i = b;
        for (; i + 3 < e; i += 4) {
            int4 ea = eg[i + half];
            int4 eb = eg[i + 2 + half];
            uint2 pa = hu[(size_t)ea.x * 32 + cl];
            uint2 pb = hu[(size_t)eb.x * 32 + cl];
            float wa = __int_as_float(ea.z), wb = __int_as_float(eb.z);
            a0 += wa * lo2f(pa.x) + wb * lo2f(pb.x);
            a1 += wa * hi2f(pa.x) + wb * hi2f(pb.x);
            a2 += wa * lo2f(pa.y) + wb * lo2f(pb.y);
            a3 += wa * hi2f(pa.y) + wb * hi2f(pb.y);
        }
        for (; i < e; i += 2) {
            int idx = i + half;
            int4 ee = eg[idx < e ? idx : i];
            float w = (idx < e) ? __int_as_float(ee.z) : 0.0f;
            uint2 p = hu[(size_t)ee.x * 32 + cl];
            a0 += w * lo2f(p.x); a1 += w * hi2f(p.x);
            a2 += w * lo2f(p.y); a3 += w * hi2f(p.y);
        }
        a0 += __shfl_xor(a0, 32); a1 += __shfl_xor(a1, 32);
        a2 += __shfl_xor(a2, 32); a3 += __shfl_xor(a3, 32);
        float sc = scale[n];
        r0 += fmaxf(a0 * sc, 0.0f); r1 += fmaxf(a1 * sc, 0.0f);
        r2 += fmaxf(a2 * sc, 0.0f); r3 += fmaxf(a3 * sc, 0.0f);
    }
    atomicAdd(&ro[cur * OUT_DIM + 4 * cl + 2 * half], half ? r2 : r0);
    atomicAdd(&ro[cur * OUT_DIM + 4 * cl + 2 * half + 1], half ? r3 : r1);
}

// ---------------- MFMA bf16 GEMM core: 128x128 tile, BK=64, swizzled global_load_lds ------

__device__ __forceinline__ void gemm_core(short* As, short* Bs,
    const unsigned short* __restrict__ A, const unsigned short* __restrict__ A2,
    const unsigned short* __restrict__ Bt, unsigned short* __restrict__ C,
    const float* __restrict__ rowScaleC, int K1, int K2, int N,
    int relu, int scaleC, int m0, int n0) {
    int tid = threadIdx.x;
    int lane = tid & 63, wave = tid >> 6;
    int wm = (wave >> 1) * 64, wn = (wave & 1) * 64;
    int quad = lane >> 4, r16 = lane & 15;
    const int K = K1 + K2;
    f32x4 acc[4][4] = {};
    int srow = lane >> 3;                     // 0..7 (row within 8-row DMA group)
    int sk   = ((lane & 7) ^ srow) * 8;       // swizzled source k-chunk (elems)
    int xorc = r16 & 7;
    short* ldsA = As + wave * 2048;           // wave stages rows [wave*32, wave*32+32)
    short* ldsB = Bs + wave * 2048;

    for (int k0 = 0; k0 < K; k0 += 64) {
        int kk = k0 + sk;
#pragma unroll
        for (int h = 0; h < 4; ++h) {
            int r = wave * 32 + h * 8 + srow;
            const unsigned short* Ap = (k0 < K1)
                ? A  + (size_t)(m0 + r) * K1 + kk
                : A2 + (size_t)(m0 + r) * K2 + (kk - K1);
            gll16(Ap, ldsA + h * 512);
            gll16(Bt + (size_t)(n0 + r) * K + kk, ldsB + h * 512);
        }
        __syncthreads();
#pragma unroll
        for (int c = 0; c < 2; ++c) {
            s16x8 af[4], bfr[4];
            int pc = (((c * 4 + quad) ^ xorc) << 3);
#pragma unroll
            for (int i = 0; i < 4; ++i)
                af[i] = *(const s16x8*)(As + (wm + i * 16 + r16) * 64 + pc);
#pragma unroll
            for (int j = 0; j < 4; ++j)
                bfr[j] = *(const s16x8*)(Bs + (wn + j * 16 + r16) * 64 + pc);
#pragma unroll
            for (int i = 0; i < 4; ++i)
#pragma unroll
                for (int j = 0; j < 4; ++j)
                    acc[i][j] = MFMA_BF16(af[i], bfr[j], acc[i][j]);
        }
        __syncthreads();
    }

#pragma unroll
    for (int i = 0; i < 4; ++i) {
        int mbase = m0 + wm + i * 16 + quad * 4;
#pragma unroll
        for (int r = 0; r < 4; ++r) {
            int m = mbase + r;
            float sc = scaleC ? rowScaleC[m] : 1.0f;
#pragma unroll
            for (int j = 0; j < 4; ++j) {
                float v = acc[i][j][r] * sc;
                if (relu) v = fmaxf(v, 0.0f);
                C[(size_t)m * N + n0 + wn + j * 16 + r16] = f2b(v);
            }
        }
    }
}

template <int RELU, int SCALE_C>
__global__ __launch_bounds__(256) void gemm_mfma(
    const unsigned short* __restrict__ A, const unsigned short* __restrict__ A2,
    const unsigned short* __restrict__ Bt, unsigned short* __restrict__ C,
    const float* __restrict__ rowScaleC, int K1, int K2, int N) {
    __shared__ short As[8192];
    __shared__ short Bs[8192];
    gemm_core(As, Bs, A, A2, Bt, C, rowScaleC, K1, K2, N, RELU, SCALE_C,
              blockIdx.x * 128, blockIdx.y * 128);
}

// -------- dual GEMM, 128x256 tile, 512 threads (8 waves): conv1 (z=0, relu) / fc1+LN (z=1) ----

__global__ __launch_bounds__(512) void gemm_dual(
    const unsigned short* __restrict__ A0, const unsigned short* __restrict__ B0,
    unsigned short* __restrict__ C0,
    const unsigned short* __restrict__ A1, const unsigned short* __restrict__ B1,
    unsigned short* __restrict__ C1,
    const float* __restrict__ gamma, const float* __restrict__ beta) {
    __shared__ short As[4096];   // [128][32]
    __shared__ short Bs[8192];   // [256][32]
    __shared__ float lns[128][4];
    __shared__ float lnq[128][4];
    const unsigned short* A  = blockIdx.z ? A1 : A0;
    const unsigned short* Bt = blockIdx.z ? B1 : B0;
    unsigned short* C        = blockIdx.z ? C1 : C0;
    int tid = threadIdx.x;
    int lane = tid & 63, wave = tid >> 6;      // 0..7
    int wm = (wave >> 2) * 64, wn = (wave & 3) * 64;
    int quad = lane >> 4, r16 = lane & 15;
    int m0 = blockIdx.x * 128;
    f32x4 acc[4][4] = {};
    int lrow = lane >> 2;
    int kc = (lane & 3) * 8;
    short* ldsA = As + wave * 512;
    short* ldsB = Bs + wave * 512;

    for (int k0 = 0; k0 < 128; k0 += 32) {
        int kk = k0 + kc;
        int rr = wave * 16 + lrow;  // 0..127
        gll16(A + (size_t)(m0 + rr) * 128 + kk, ldsA);
        gll16(Bt + (size_t)rr * 128 + kk, ldsB);
        gll16(Bt + (size_t)(128 + rr) * 128 + kk, ldsB + 4096);
        __syncthreads();
        s16x8 af[4], bfr[4];
#pragma unroll
        for (int i = 0; i < 4; ++i)
            af[i] = *(const s16x8*)(As + (wm + i * 16 + r16) * 32 + quad * 8);
#pragma unroll
        for (int j = 0; j < 4; ++j)
            bfr[j] = *(const s16x8*)(Bs + (wn + j * 16 + r16) * 32 + quad * 8);
#pragma unroll
        for (int i = 0; i < 4; ++i)
#pragma unroll
            for (int j = 0; j < 4; ++j)
                acc[i][j] = MFMA_BF16(af[i], bfr[j], acc[i][j]);
        __syncthreads();
    }

    if (blockIdx.z == 0) {
        // conv1: relu, store
#pragma unroll
        for (int i = 0; i < 4; ++i) {
            int mbase = m0 + wm + i * 16 + quad * 4;
#pragma unroll
            for (int r = 0; r < 4; ++r) {
                int m = mbase + r;
#pragma unroll
                for (int j = 0; j < 4; ++j)
                    C[(size_t)m * 256 + wn + j * 16 + r16] = f2b(fmaxf(acc[i][j][r], 0.0f));
            }
        }
    } else {
        // fc1: LayerNorm(affine) + relu from fp32 accumulators
#pragma unroll
        for (int i = 0; i < 4; ++i)
#pragma unroll
            for (int r = 0; r < 4; ++r) {
                float s = 0.0f, q = 0.0f;
#pragma unroll
                for (int j = 0; j < 4; ++j) { float v = acc[i][j][r]; s += v; q += v * v; }
#pragma unroll
                for (int m = 1; m < 16; m <<= 1) { s += __shfl_xor(s, m); q += __shfl_xor(q, m); }
                if (r16 == 0) {
                    int row = wm + i * 16 + quad * 4 + r;
                    lns[row][wave & 3] = s;
                    lnq[row][wave & 3] = q;
                }
            }
        __syncthreads();
#pragma unroll
        for (int i = 0; i < 4; ++i) {
#pragma unroll
            for (int r = 0; r < 4; ++r) {
                int row = wm + i * 16 + quad * 4 + r;
                float s = lns[row][0] + lns[row][1] + lns[row][2] + lns[row][3];
                float q = lnq[row][0] + lnq[row][1] + lnq[row][2] + lnq[row][3];
                float mu = s * (1.0f / HID4);
                float var = q * (1.0f / HID4) - mu * mu;
                float rs = rsqrtf(var + LN_EPS);
                int m = m0 + row;
#pragma unroll
                for (int j = 0; j < 4; ++j) {
                    int col = wn + j * 16 + r16;
                    float v = (acc[i][j][r] - mu) * rs * gamma[col] + beta[col];
                    C[(size_t)m * 256 + col] = f2b(fmaxf(v, 0.0f));
                }
            }
        }
    }
}

// ---------------- normalize ----------------

__global__ void normalize_out(const float* __restrict__ ro, float* __restrict__ out) {
    int g = blockIdx.x;
    int d = threadIdx.x;  // 128 threads = 2 waves
    float v = ro[g * OUT_DIM + d];
    float ss = v * v;
#pragma unroll
    for (int m = 1; m < 64; m <<= 1) ss += __shfl_xor(ss, m);
    __shared__ float s2[2];
    if ((d & 63) == 0) s2[d >> 6] = ss;
    __syncthreads();
    float tot = s2[0] + s2[1];
    float norm = fmaxf(sqrtf(tot), 1e-12f);
    out[g * OUT_DIM + d] = v / norm;
}

// ---------------- launch ----------------

extern "C" void kernel_launch(void* const* d_in, const int* in_sizes, int n_in,
                              void* d_out, int out_size, void* d_ws, size_t ws_size,
                              hipStream_t stream) {
    const float* x    = (const float*)d_in[0];
    const float* w    = (const float*)d_in[1];
    const float* W1   = (const float*)d_in[2];
    const float* fc1W = (const float*)d_in[3];
    const float* gam  = (const float*)d_in[4];
    const float* bet  = (const float*)d_in[5];
    const float* W2   = (const float*)d_in[6];
    const float* W3   = (const float*)d_in[7];
    const int* src = (const int*)d_in[8];
    const int* dst = (const int*)d_in[9];
    const int* gid = (const int*)d_in[10];
    float* out = (float*)d_out;

    float* ws = (float*)d_ws;
    float* out_inv = ws + 0;                                 // 40000
    float* in_inv  = ws + 40000;                             // 40000
    float* ew      = ws + 80000;                             // 320000
    int*   cnt_out = (int*)(ws + 400000);                    // 40000 (memset group start)
    int*   cnt_in  = (int*)(ws + 440000);                    // 40000 (memset group)
    float* ro      = ws + 480000;                            // 8192 (memset group end)
    unsigned short* W1t  = (unsigned short*)(ws + 488192);   // [256][128]
    unsigned short* fc1t = (unsigned short*)(ws + 504576);   // [256][128]
    unsigned short* W2t  = (unsigned short*)(ws + 520960);   // [256][512]
    unsigned short* W3t  = (unsigned short*)(ws + 586496);   // [128][256]
    int*   partial = (int*)(ws + 602880);                    // 40
    int*   off     = (int*)(ws + 602920);                    // 40001 ints
    int4*  es      = (int4*)(ws + 642924);                   // 320000 int4 (16B-aligned)
    unsigned short* xb    = (unsigned short*)(ws + 1923000); // [M_PAD][128] ; later Q3b
    unsigned short* Q3b   = xb;
    unsigned short* agg1b = (unsigned short*)(ws + 4487100); // [M_PAD][128..256] ; later x2b
    unsigned short* x2b   = agg1b;
    unsigned short* x1b   = (unsigned short*)(ws + 9615300); // [M_PAD][256]
    unsigned short* f1b   = (unsigned short*)(ws + 14743500);// [M_PAD][256]
    unsigned short* P2b   = (unsigned short*)(ws + 19871700);// [M_PAD][256]
    int*   rank    = (int*)(ws + 25000000);                  // 320000 ints

    // one memset covers cnt_out | cnt_in | ro (contiguous)
    hipMemsetAsync(cnt_out, 0, (2 * 40000 + N_GRAPHS * OUT_DIM) * sizeof(float), stream);

    // fused conversions + edge weights + degree histograms (+ per-edge dst-bucket rank)
    prep_all<<<(PREP_TOT + 255) / 256, 256, 0, stream>>>(x, W1, fc1W, W2, W3, w, src, dst,
                                                         xb, W1t, fc1t, W2t, W3t, ew,
                                                         cnt_out, cnt_in, rank);
    scan_part<<<40, 256, 0, stream>>>(cnt_in, partial);
    scan_final<<<40, 1024, 0, stream>>>(cnt_in, cnt_out, partial, off, out_inv, in_inv);
    // atomic-free CSR scatter
    csr_fill<<<(N_EDGES + 255) / 256, 256, 0, stream>>>(src, dst, ew, out_inv, off, rank, es);

    // conv1 gather, then fused conv1+fc1(+LN) GEMM (512-thread, 128x256 tile, z-grid)
    gather_nodes<IN_DIM, 0, 0><<<N_NODES, 64, 0, stream>>>(xb, off, es, in_inv, agg1b);
    {
        dim3 grid(M_PAD / 128, 1, 2);
        gemm_dual<<<grid, 512, 0, stream>>>(agg1b, W1t, x1b, xb, fc1t, f1b, gam, bet);
    }

    // conv2
    {
        dim3 grid(M_PAD / 128, HID4 / 128);
        gemm_mfma<0, 1><<<grid, 256, 0, stream>>>(x1b, f1b, W2t, P2b, out_inv,
                                                  HID4, HID4, HID4);
    }
    gather_nodes<HID4, 1, 1><<<N_NODES, 64, 0, stream>>>(P2b, off, es, in_inv, x2b);

    // conv3
    {
        dim3 grid(M_PAD / 128, OUT_DIM / 128);
        gemm_mfma<0, 1><<<grid, 256, 0, stream>>>(x2b, nullptr, W3t, Q3b, out_inv,
                                                  HID4, 0, OUT_DIM);
    }
    // conv3 gather fused with readout (x3 never materialized)
    gather3_ro<<<(N_NODES + G3_NPB - 1) / G3_NPB, 64, 0, stream>>>(Q3b, off, es, in_inv,
                                                                   gid, ro);
    normalize_out<<<N_GRAPHS, 128, 0, stream>>>(ro, out);
}